// Round 6
// baseline (6886.584 us; speedup 1.0000x reference)
//
#include <hip/hip_runtime.h>

typedef __bf16 bf16x8 __attribute__((ext_vector_type(8)));
typedef float f32x4 __attribute__((ext_vector_type(4)));
typedef unsigned short u16;
typedef u16 ushort8 __attribute__((ext_vector_type(8)));

#define BB 256
#define TT 512
#define II 64
#define HH 512

// ws layout:
// [0x000000) h0buf : 2 * 256KB (fragment-order bf16)
// [0x080000) h1buf : 2 * 256KB (fragment-order bf16)
// [0x100000) h1fin : 256*512 f32
// [0x180000) barrier slots: 4 groups x 64 WG x 4 waves x u32 (4KB)
// [0x190000) xfrag : 512t*16R*2kk*64lane*8 bf16 = 16 MB (optional)
#define OFF_H1BUF 0x80000
#define OFF_H1FIN 0x100000
#define OFF_BAR   0x180000
#define OFF_XFRAG 0x190000
#define WS_NEED   (0x190000 + (size_t)(1 << 24))

__device__ __forceinline__ u16 f2bf(float f) {
  unsigned u = __builtin_bit_cast(unsigned, f);
  u = (u + 0x7FFFu + ((u >> 16) & 1u)) >> 16;   // RNE truncate to bf16
  return (u16)u;
}
__device__ __forceinline__ float sigmf(float v) {
  return 1.0f / (1.0f + __expf(-v));
}
__device__ __forceinline__ float tanh_s(float v) {
  float a = __builtin_fabsf(v);
  float e = __expf(-2.0f * a);
  float t = (1.0f - e) / (1.0f + e);
  return __builtin_copysignf(t, v);
}
__device__ __forceinline__ f32x4 mfma16(bf16x8 a, bf16x8 b, f32x4 c) {
  return __builtin_amdgcn_mfma_f32_16x16x32_bf16(a, b, c, 0, 0, 0);
}
// fragment-order offset (u16 units): chunk (R, kk, lane) of 8 bf16
__device__ __forceinline__ size_t fragoff(int R, int kk, int lane) {
  return ((size_t)(R * 16 + kk) * 64 + lane) * 8;
}
// agent-scope (cross-XCD coherent) 16B chunk load as 2x8B relaxed atomics
__device__ __forceinline__ bf16x8 ld_h8(const u16* p) {
  union { unsigned long long q[2]; ushort8 v; } u;
  u.q[0] = __hip_atomic_load((unsigned long long*)p, __ATOMIC_RELAXED,
                             __HIP_MEMORY_SCOPE_AGENT);
  u.q[1] = __hip_atomic_load((unsigned long long*)(p + 4), __ATOMIC_RELAXED,
                             __HIP_MEMORY_SCOPE_AGENT);
  return __builtin_bit_cast(bf16x8, u.v);
}
__device__ __forceinline__ bf16x8 ld_lds8(const u16* p) {
  return __builtin_bit_cast(bf16x8, *(const ushort8*)p);
}

__global__ void init_bar_k(unsigned* bar) {
  for (int i = threadIdx.x; i < 1024; i += blockDim.x) bar[i] = 0u;
}

// x -> fragment-order bf16: xfrag[t][R][kk][lane][8], one thread per chunk.
__global__ void xpose_k(const float* __restrict__ x, u16* __restrict__ xfrag) {
  const size_t idx = (size_t)blockIdx.x * 256 + threadIdx.x;  // 2^20 chunks
  const int lane = idx & 63;
  const int kk = (idx >> 6) & 1;
  const int R = (idx >> 7) & 15;
  const int t = (int)(idx >> 11);
  const int row = R * 16 + (lane & 15);
  const int col = kk * 32 + (lane >> 4) * 8;
  const float* src = x + ((size_t)row * TT + t) * II + col;
  ushort8 v;
#pragma unroll
  for (int j = 0; j < 8; ++j) v[j] = f2bf(src[j]);
  *(ushort8*)(xfrag + idx * 8) = v;
}

// Persistent fused 2-layer LSTM. grid=256 (1 WG/CU), block=256 (4 waves).
// WG(bid): bt = bid>>6 (batch tile of 64 rows), ut = bid&63 (8 hidden units).
// Wave wid: rows [bt*64 + wid*16, +16); per-wave R = bt*4 + wid.
// W1 (K=1024, 64 frags) REGISTER-resident per wave (~256 VGPR; 1 wave/SIMD
// occupancy makes up to 512 free). W0 (K=576) LDS-resident. One hf[16] array
// reused for h0-phase then h1-phase to stay under the 450-reg spill line.
// Barrier: per-batch-tile, per-WAVE monotonic u32 slots; every wave polls all
// 256 slots itself -> NO __syncthreads in the loop.
__global__ __launch_bounds__(256, 1) void lstm_persist(
    const float* __restrict__ x, const u16* __restrict__ xfrag,
    const float* __restrict__ Wih0, const float* __restrict__ Whh0,
    const float* __restrict__ bih0, const float* __restrict__ bhh0,
    const float* __restrict__ Wih1, const float* __restrict__ Whh1,
    const float* __restrict__ bih1, const float* __restrict__ bhh1,
    u16* __restrict__ h0buf, u16* __restrict__ h1buf,
    float* __restrict__ h1fin, unsigned* bar) {
  __shared__ u16 w0s[32 * 600];

  const int tid = threadIdx.x;
  const int lane = tid & 63;
  const int wid = tid >> 6;
  const int bid = blockIdx.x;
  const int ut = bid & 63, bt = bid >> 6;
  const int u0 = ut * 8;
  const int cc = lane & 15, grp = lane >> 4;

  unsigned* slots = bar + (size_t)bt * 256;   // 64 WGs x 4 waves u32

  // ---- stage W0 slice (32 gate-rows x 576) into LDS as bf16 ----
  {
    const int srow = tid >> 3, sub = tid & 7;
    const int g = (srow >> 3) * 512 + u0 + (srow & 7);
    const float* wih = Wih0 + (size_t)g * 64;
    const float* whh = Whh0 + (size_t)g * 512;
    const int e0 = sub * 72;
    for (int e = e0; e < e0 + 72; ++e) {
      float v = (e < 64) ? wih[e] : whh[e - 64];
      w0s[srow * 600 + e] = f2bf(v);
    }
  }

  // ---- preload W1 fragments into registers (64 frags = 256 VGPR) ----
  bf16x8 b1[32][2];
#pragma unroll
  for (int kk = 0; kk < 32; ++kk) {
#pragma unroll
    for (int nf = 0; nf < 2; ++nf) {
      const int srow = nf * 16 + cc;
      const int g = (srow >> 3) * 512 + u0 + (srow & 7);
      const int k = kk * 32 + grp * 8;
      const float* src = (k < 512) ? (Wih1 + (size_t)g * 512 + k)
                                   : (Whh1 + (size_t)g * 512 + (k - 512));
      ushort8 t;
#pragma unroll
      for (int j = 0; j < 8; ++j) t[j] = f2bf(src[j]);
      b1[kk][nf] = __builtin_bit_cast(bf16x8, t);
    }
  }

  float bias0[2], bias1[2];
#pragma unroll
  for (int nf = 0; nf < 2; ++nf) {
    const int srow = nf * 16 + cc;
    const int g = (srow >> 3) * 512 + u0 + (srow & 7);
    bias0[nf] = bih0[g] + bhh0[g];
    bias1[nf] = bih1[g] + bhh1[g];
  }

  const int row0 = bt * 64 + wid * 16;
  const int Rw = bt * 4 + wid;              // this wave's 16-row block
  const int arow = row0 + cc;               // fallback-path row
  const float* xbase = x + (size_t)arow * (TT * II) + grp * 8;
  const bool usexf = (xfrag != nullptr);
  float c0[4] = {0.f, 0.f, 0.f, 0.f};
  float c1[4] = {0.f, 0.f, 0.f, 0.f};

  ushort8 xpre[2];
  float xr[16];
  if (usexf) {
#pragma unroll
    for (int kk = 0; kk < 2; ++kk)
      xpre[kk] = *(const ushort8*)(xfrag + ((size_t)0 * 16 + Rw) * 1024 +
                                   (size_t)kk * 512 + lane * 8);
  } else {
#pragma unroll
    for (int j = 0; j < 16; ++j) xr[j] = xbase[(j >> 3) * 32 + (j & 7)];
  }

  __syncthreads();   // weights staged (only pre-loop sync)

#pragma unroll 1
  for (int s = 0; s <= 512; ++s) {
    const bool doL0 = (s < 512);
    const bool h0ok = (s >= 1);
    const bool h1ok = (s >= 2);
    const u16* h0rd = h0buf + (size_t)((s + 1) & 1) * (131072);
    const u16* h1rd = h1buf + (size_t)(s & 1) * (131072);
    u16* h0wr = h0buf + (size_t)(s & 1) * (131072);
    u16* h1wr = h1buf + (size_t)((s + 1) & 1) * (131072);

    f32x4 a00 = {bias0[0], bias0[0], bias0[0], bias0[0]};
    f32x4 a01 = {bias0[1], bias0[1], bias0[1], bias0[1]};
    f32x4 a10 = {bias1[0], bias1[0], bias1[0], bias1[0]};
    f32x4 a11 = {bias1[1], bias1[1], bias1[1], bias1[1]};

    bf16x8 xf[2], hf[16];

    if (doL0) {
      if (usexf) {
#pragma unroll
        for (int kk = 0; kk < 2; ++kk)
          xf[kk] = __builtin_bit_cast(bf16x8, xpre[kk]);
        // prefetch next step's x NOW so its latency hides under compute
        const size_t sp = (size_t)((s + 1) & 511);
#pragma unroll
        for (int kk = 0; kk < 2; ++kk)
          xpre[kk] = *(const ushort8*)(xfrag + (sp * 16 + Rw) * 1024 +
                                       (size_t)kk * 512 + lane * 8);
      } else {
#pragma unroll
        for (int kk = 0; kk < 2; ++kk) {
          ushort8 t;
#pragma unroll
          for (int j = 0; j < 8; ++j) t[j] = f2bf(xr[kk * 8 + j]);
          xf[kk] = __builtin_bit_cast(bf16x8, t);
        }
        const size_t sp = (size_t)((s + 1) & 511);
#pragma unroll
        for (int j = 0; j < 16; ++j)
          xr[j] = xbase[sp * II + (j >> 3) * 32 + (j & 7)];
      }
    }

    const int lb = grp * 8;

    // ======== phase A: hf = h0[s-1] fragments ========
    if (h0ok) {
      const u16* p = h0rd + fragoff(Rw, 0, lane);
#pragma unroll
      for (int kk = 0; kk < 16; ++kk) hf[kk] = ld_h8(p + (size_t)kk * 512);
    }
    // L0 x-part (independent of hf)
    if (doL0) {
#pragma unroll
      for (int kk = 0; kk < 2; ++kk) {
        bf16x8 bA = ld_lds8(&w0s[cc * 600 + kk * 32 + lb]);
        bf16x8 bB = ld_lds8(&w0s[(16 + cc) * 600 + kk * 32 + lb]);
        a00 = mfma16(xf[kk], bA, a00);
        a01 = mfma16(xf[kk], bB, a01);
      }
    }
    if (h0ok) {
      // L0 h-part (W0 from LDS)
      if (doL0) {
#pragma unroll
        for (int kk = 0; kk < 16; ++kk) {
          bf16x8 bA = ld_lds8(&w0s[cc * 600 + (kk + 2) * 32 + lb]);
          bf16x8 bB = ld_lds8(&w0s[(16 + cc) * 600 + (kk + 2) * 32 + lb]);
          a00 = mfma16(hf[kk], bA, a00);
          a01 = mfma16(hf[kk], bB, a01);
        }
      }
      // L1 ih-part (W1 from registers)
#pragma unroll
      for (int kk = 0; kk < 16; ++kk) {
        a10 = mfma16(hf[kk], b1[kk][0], a10);
        a11 = mfma16(hf[kk], b1[kk][1], a11);
      }
    }
    // ======== phase B: hf = h1[s-1] fragments (register reuse) ========
    if (h1ok) {
      const u16* p = h1rd + fragoff(Rw, 0, lane);
#pragma unroll
      for (int kk = 0; kk < 16; ++kk) hf[kk] = ld_h8(p + (size_t)kk * 512);
#pragma unroll
      for (int kk = 0; kk < 16; ++kk) {
        a10 = mfma16(hf[kk], b1[16 + kk][0], a10);
        a11 = mfma16(hf[kk], b1[16 + kk][1], a11);
      }
    }

    // writer chunk params: kk_w = ut>>2, lane' = (ut&3)*16 + grp*4 + r
    const int kkw = ut >> 2, lpb = (ut & 3) * 16;
    // ---- layer0 cell ----
    if (doL0) {
#pragma unroll
      for (int r = 0; r < 4; ++r) {
        float f_p = __shfl_xor(a00[r], 8);
        float o_p = __shfl_xor(a01[r], 8);
        float ig = sigmf(a00[r]);
        float fg = sigmf(f_p);
        float gg = tanh_s(a01[r]);
        float og = sigmf(o_p);
        float cn = fg * c0[r] + ig * gg;
        c0[r] = cn;
        float hv = og * tanh_s(cn);
        unsigned myb = f2bf(hv);
        unsigned nb = (unsigned)__shfl_down((int)myb, 1);
        if (cc < 8 && (cc & 1) == 0) {
          unsigned* p = (unsigned*)(h0wr +
              fragoff(Rw, kkw, lpb + grp * 4 + r) + cc);
          __hip_atomic_store(p, myb | (nb << 16), __ATOMIC_RELAXED,
                             __HIP_MEMORY_SCOPE_AGENT);
        }
      }
    }
    // ---- layer1 cell ----
    if (h0ok) {
#pragma unroll
      for (int r = 0; r < 4; ++r) {
        float f_p = __shfl_xor(a10[r], 8);
        float o_p = __shfl_xor(a11[r], 8);
        float ig = sigmf(a10[r]);
        float fg = sigmf(f_p);
        float gg = tanh_s(a11[r]);
        float og = sigmf(o_p);
        float cn = fg * c1[r] + ig * gg;
        c1[r] = cn;
        float hv = og * tanh_s(cn);
        unsigned myb = f2bf(hv);
        unsigned nb = (unsigned)__shfl_down((int)myb, 1);
        if (cc < 8 && (cc & 1) == 0) {
          unsigned* p = (unsigned*)(h1wr +
              fragoff(Rw, kkw, lpb + grp * 4 + r) + cc);
          __hip_atomic_store(p, myb | (nb << 16), __ATOMIC_RELAXED,
                             __HIP_MEMORY_SCOPE_AGENT);
        }
        if (cc < 8 && s == 512)
          h1fin[(size_t)(row0 + grp * 4 + r) * HH + u0 + cc] = hv;
      }
    }

    // ---- per-wave barrier (no __syncthreads): arrive own slot, poll all ----
    if (s < 512) {
      asm volatile("s_waitcnt vmcnt(0)" ::: "memory");  // own h-stores acked
      const unsigned tgt = (unsigned)(s + 1);
      if (lane == 0)
        __hip_atomic_store(&slots[ut * 4 + wid], tgt, __ATOMIC_RELAXED,
                           __HIP_MEMORY_SCOPE_AGENT);
      // lane l polls WG l's 4 wave-slots (16B) -> coalesced 1KB wave read
      const unsigned long long* sl =
          (const unsigned long long*)slots + (size_t)lane * 2;
      for (;;) {
        unsigned long long q0 = __hip_atomic_load(sl, __ATOMIC_RELAXED,
                                                  __HIP_MEMORY_SCOPE_AGENT);
        unsigned long long q1 = __hip_atomic_load(sl + 1, __ATOMIC_RELAXED,
                                                  __HIP_MEMORY_SCOPE_AGENT);
        bool ok = ((unsigned)q0 >= tgt) && ((unsigned)(q0 >> 32) >= tgt) &&
                  ((unsigned)q1 >= tgt) && ((unsigned)(q1 >> 32) >= tgt);
        if (__all(ok)) break;
        __builtin_amdgcn_s_sleep(2);
      }
    }
  }
}

__global__ void fc_kernel(const float* __restrict__ h1fin,
                          const float* __restrict__ Wfc,
                          const float* __restrict__ bfc,
                          float* __restrict__ out) {
  const int wid = threadIdx.x >> 6, lane = threadIdx.x & 63;
  const int b = blockIdx.x * 4 + wid;
  float sum = 0.f;
#pragma unroll
  for (int j = 0; j < 8; ++j)
    sum += h1fin[(size_t)b * 512 + lane + 64 * j] * Wfc[lane + 64 * j];
#pragma unroll
  for (int m = 32; m; m >>= 1) sum += __shfl_xor(sum, m);
  if (lane == 0) out[b] = sum + bfc[0];
}

extern "C" void kernel_launch(void* const* d_in, const int* in_sizes, int n_in,
                              void* d_out, int out_size, void* d_ws, size_t ws_size,
                              hipStream_t stream) {
  const float* x    = (const float*)d_in[0];
  const float* Wih0 = (const float*)d_in[1];
  const float* Whh0 = (const float*)d_in[2];
  const float* bih0 = (const float*)d_in[3];
  const float* bhh0 = (const float*)d_in[4];
  const float* Wih1 = (const float*)d_in[5];
  const float* Whh1 = (const float*)d_in[6];
  const float* bih1 = (const float*)d_in[7];
  const float* bhh1 = (const float*)d_in[8];
  const float* Wfc  = (const float*)d_in[9];
  const float* bfc  = (const float*)d_in[10];

  char* ws = (char*)d_ws;
  u16* h0buf = (u16*)(ws);
  u16* h1buf = (u16*)(ws + OFF_H1BUF);
  float* h1fin = (float*)(ws + OFF_H1FIN);
  unsigned* bar = (unsigned*)(ws + OFF_BAR);
  u16* xfrag = (ws_size >= WS_NEED) ? (u16*)(ws + OFF_XFRAG) : nullptr;

  init_bar_k<<<1, 256, 0, stream>>>(bar);
  if (xfrag) xpose_k<<<4096, 256, 0, stream>>>(x, xfrag);
  lstm_persist<<<256, 256, 0, stream>>>(x, xfrag, Wih0, Whh0, bih0, bhh0,
                                        Wih1, Whh1, bih1, bhh1,
                                        h0buf, h1buf, h1fin, bar);
  fc_kernel<<<64, 256, 0, stream>>>(h1fin, Wfc, bfc, (float*)d_out);
}

// Round 7
// 4198.227 us; speedup vs baseline: 1.6404x; 1.6404x over previous
//
#include <hip/hip_runtime.h>

typedef __bf16 bf16x8 __attribute__((ext_vector_type(8)));
typedef float f32x4 __attribute__((ext_vector_type(4)));
typedef unsigned short u16;
typedef u16 ushort8 __attribute__((ext_vector_type(8)));

#define BB 256
#define TT 512
#define II 64
#define HH 512
#define SLOT 131072   // u16 per h ring slot (256 KB)

// ws layout:
// [0x000000) h0ring : 4 * 256KB (fragment-order bf16)
// [0x100000) h1ring : 2 * 256KB
// [0x180000) h1fin  : 256*512 f32
// [0x200000) barA   : 1024 u32 ; barB at +4KB (16KB region total)
// [0x210000) xfrag  : 16 MB (optional)
#define OFF_H1RING 0x100000
#define OFF_H1FIN  0x180000
#define OFF_BAR    0x200000
#define OFF_XFRAG  0x210000
#define WS_NEED    (0x210000 + (size_t)(1 << 24))

__device__ __forceinline__ u16 f2bf(float f) {
  unsigned u = __builtin_bit_cast(unsigned, f);
  u = (u + 0x7FFFu + ((u >> 16) & 1u)) >> 16;   // RNE truncate to bf16
  return (u16)u;
}
__device__ __forceinline__ float sigmf(float v) {
  return 1.0f / (1.0f + __expf(-v));
}
__device__ __forceinline__ float tanh_s(float v) {
  float a = __builtin_fabsf(v);
  float e = __expf(-2.0f * a);
  float t = (1.0f - e) / (1.0f + e);
  return __builtin_copysignf(t, v);
}
__device__ __forceinline__ f32x4 mfma16(bf16x8 a, bf16x8 b, f32x4 c) {
  return __builtin_amdgcn_mfma_f32_16x16x32_bf16(a, b, c, 0, 0, 0);
}
// fragment-order offset (u16 units): chunk (R, kk, lane) of 8 bf16
__device__ __forceinline__ size_t fragoff(int R, int kk, int lane) {
  return ((size_t)(R * 16 + kk) * 64 + lane) * 8;
}
// agent-scope (cross-XCD coherent) 16B chunk load as 2x8B relaxed atomics
__device__ __forceinline__ bf16x8 ld_h8(const u16* p) {
  union { unsigned long long q[2]; ushort8 v; } u;
  u.q[0] = __hip_atomic_load((unsigned long long*)p, __ATOMIC_RELAXED,
                             __HIP_MEMORY_SCOPE_AGENT);
  u.q[1] = __hip_atomic_load((unsigned long long*)(p + 4), __ATOMIC_RELAXED,
                             __HIP_MEMORY_SCOPE_AGENT);
  return __builtin_bit_cast(bf16x8, u.v);
}
__device__ __forceinline__ bf16x8 ld_lds8(const u16* p) {
  return __builtin_bit_cast(bf16x8, *(const ushort8*)p);
}

__global__ void init_bar_k(unsigned* bar) {
  for (int i = threadIdx.x; i < 4096; i += blockDim.x) bar[i] = 0u;
}

// x -> fragment-order bf16: xfrag[t][R][kk][lane][8], one thread per chunk.
__global__ void xpose_k(const float* __restrict__ x, u16* __restrict__ xfrag) {
  const size_t idx = (size_t)blockIdx.x * 256 + threadIdx.x;  // 2^20 chunks
  const int lane = idx & 63;
  const int kk = (idx >> 6) & 1;
  const int R = (idx >> 7) & 15;
  const int t = (int)(idx >> 11);
  const int row = R * 16 + (lane & 15);
  const int col = kk * 32 + (lane >> 4) * 8;
  const float* src = x + ((size_t)row * TT + t) * II + col;
  ushort8 v;
#pragma unroll
  for (int j = 0; j < 8; ++j) v[j] = f2bf(src[j]);
  *(ushort8*)(xfrag + idx * 8) = v;
}

// Persistent fused 2-layer LSTM, deep-skew schedule. grid=256, block=256.
// WG(bid): bt=bid>>6 (64-row batch tile), ut=bid&63 (8 hidden units).
// Step s: L0 computes t=s (critical path); SHADOW computes L1 t=s-2 using
// h0[s-2], h1[s-3] -- both already globally visible, so all L1 work runs
// between arriveA and pollA, hidden in the straggler/poll window.
// Guards: arriveA(s+1) after h0[s] drain (wave0 polls at step end);
//         arriveB(s+1) after shadow h1 drain (polled at next shadow start,
//         one L0-phase of slack -> rarely spins).
// Ring depth vs straggler overwrite: h0 4-deep, h1 2-deep (proofs in notes).
__global__ __launch_bounds__(256, 1) void lstm_persist(
    const float* __restrict__ x, const u16* __restrict__ xfrag,
    const float* __restrict__ Wih0, const float* __restrict__ Whh0,
    const float* __restrict__ bih0, const float* __restrict__ bhh0,
    const float* __restrict__ Wih1, const float* __restrict__ Whh1,
    const float* __restrict__ bih1, const float* __restrict__ bhh1,
    u16* __restrict__ h0ring, u16* __restrict__ h1ring,
    float* __restrict__ h1fin, unsigned* __restrict__ barA,
    unsigned* __restrict__ barB) {
  __shared__ u16 w0s[32 * 600];
  __shared__ u16 w1s[32 * 1048];

  const int tid = threadIdx.x;
  const int lane = tid & 63;
  const int wid = tid >> 6;
  const int bid = blockIdx.x;
  const int ut = bid & 63, bt = bid >> 6;
  const int u0 = ut * 8;
  const int cc = lane & 15, grp = lane >> 4;

  unsigned* slotsA = barA + (size_t)bt * 256;   // 64 WG x 4 wave u32
  unsigned* slotsB = barB + (size_t)bt * 256;

  // ---- stage W0 slice (32 gate-rows x 576) into LDS as bf16 ----
  {
    const int srow = tid >> 3, sub = tid & 7;
    const int g = (srow >> 3) * 512 + u0 + (srow & 7);
    const float* wih = Wih0 + (size_t)g * 64;
    const float* whh = Whh0 + (size_t)g * 512;
    const int e0 = sub * 72;
    for (int e = e0; e < e0 + 72; ++e) {
      float v = (e < 64) ? wih[e] : whh[e - 64];
      w0s[srow * 600 + e] = f2bf(v);
    }
  }
  // ---- stage W1 slice (32 gate-rows x 1024) into LDS as bf16 ----
  {
    const int srow = tid >> 3, sub = tid & 7;
    const int g = (srow >> 3) * 512 + u0 + (srow & 7);
    const float* wih = Wih1 + (size_t)g * 512;
    const float* whh = Whh1 + (size_t)g * 512;
    const int e0 = sub * 128;
    for (int e = e0; e < e0 + 128; ++e) {
      float v = (e < 512) ? wih[e] : whh[e - 512];
      w1s[srow * 1048 + e] = f2bf(v);
    }
  }

  float bias0[2], bias1[2];
#pragma unroll
  for (int nf = 0; nf < 2; ++nf) {
    const int srow = nf * 16 + cc;
    const int g = (srow >> 3) * 512 + u0 + (srow & 7);
    bias0[nf] = bih0[g] + bhh0[g];
    bias1[nf] = bih1[g] + bhh1[g];
  }

  const int row0 = bt * 64 + wid * 16;
  const int Rw = bt * 4 + wid;              // this wave's 16-row block
  const int arow = row0 + cc;               // fallback-path row
  const float* xbase = x + (size_t)arow * (TT * II) + grp * 8;
  const bool usexf = (xfrag != nullptr);
  float c0[4] = {0.f, 0.f, 0.f, 0.f};
  float c1[4] = {0.f, 0.f, 0.f, 0.f};

  ushort8 xpre[2];
  float xr[16];
  if (usexf) {
#pragma unroll
    for (int kk = 0; kk < 2; ++kk)
      xpre[kk] = *(const ushort8*)(xfrag + (size_t)Rw * 1024 +
                                   (size_t)kk * 512 + lane * 8);
  } else {
#pragma unroll
    for (int j = 0; j < 16; ++j) xr[j] = xbase[(j >> 3) * 32 + (j & 7)];
  }

  // writer chunk params: kk_w = ut>>2, lane' = (ut&3)*16 + grp*4 + r
  const int kkw = ut >> 2, lpb = (ut & 3) * 16;
  const int lb = grp * 8;

  __syncthreads();   // weights staged (only pre-loop sync besides barrier)

#pragma unroll 1
  for (int s = 0; s <= 513; ++s) {
    const bool doL0 = (s < 512);
    bf16x8 hf[16];

    // ======== critical path: layer0 t = s ========
    if (doL0) {
      f32x4 a00 = {bias0[0], bias0[0], bias0[0], bias0[0]};
      f32x4 a01 = {bias0[1], bias0[1], bias0[1], bias0[1]};
      bf16x8 xf[2];
      if (usexf) {
#pragma unroll
        for (int kk = 0; kk < 2; ++kk)
          xf[kk] = __builtin_bit_cast(bf16x8, xpre[kk]);
        const size_t sp = (size_t)((s + 1) & 511);
#pragma unroll
        for (int kk = 0; kk < 2; ++kk)
          xpre[kk] = *(const ushort8*)(xfrag + (sp * 16 + Rw) * 1024 +
                                       (size_t)kk * 512 + lane * 8);
      } else {
#pragma unroll
        for (int kk = 0; kk < 2; ++kk) {
          ushort8 t;
#pragma unroll
          for (int j = 0; j < 8; ++j) t[j] = f2bf(xr[kk * 8 + j]);
          xf[kk] = __builtin_bit_cast(bf16x8, t);
        }
        const size_t sp = (size_t)((s + 1) & 511);
#pragma unroll
        for (int j = 0; j < 16; ++j)
          xr[j] = xbase[sp * II + (j >> 3) * 32 + (j & 7)];
      }
      if (s >= 1) {   // issue h0[s-1] loads first (hide RTT under x MFMAs)
        const u16* p = h0ring + (size_t)((s - 1) & 3) * SLOT +
                       fragoff(Rw, 0, lane);
#pragma unroll
        for (int kk = 0; kk < 16; ++kk) hf[kk] = ld_h8(p + (size_t)kk * 512);
      }
#pragma unroll
      for (int kk = 0; kk < 2; ++kk) {
        bf16x8 bA = ld_lds8(&w0s[cc * 600 + kk * 32 + lb]);
        bf16x8 bB = ld_lds8(&w0s[(16 + cc) * 600 + kk * 32 + lb]);
        a00 = mfma16(xf[kk], bA, a00);
        a01 = mfma16(xf[kk], bB, a01);
      }
      if (s >= 1) {
#pragma unroll
        for (int kk = 0; kk < 16; ++kk) {
          bf16x8 bA = ld_lds8(&w0s[cc * 600 + (kk + 2) * 32 + lb]);
          bf16x8 bB = ld_lds8(&w0s[(16 + cc) * 600 + (kk + 2) * 32 + lb]);
          a00 = mfma16(hf[kk], bA, a00);
          a01 = mfma16(hf[kk], bB, a01);
        }
      }
      // ---- layer0 cell -> store h0[s] (ring slot s&3) ----
      u16* h0wr = h0ring + (size_t)(s & 3) * SLOT;
#pragma unroll
      for (int r = 0; r < 4; ++r) {
        float f_p = __shfl_xor(a00[r], 8);
        float o_p = __shfl_xor(a01[r], 8);
        float ig = sigmf(a00[r]);
        float fg = sigmf(f_p);
        float gg = tanh_s(a01[r]);
        float og = sigmf(o_p);
        float cn = fg * c0[r] + ig * gg;
        c0[r] = cn;
        float hv = og * tanh_s(cn);
        unsigned myb = f2bf(hv);
        unsigned nb = (unsigned)__shfl_down((int)myb, 1);
        if (cc < 8 && (cc & 1) == 0) {
          unsigned* p = (unsigned*)(h0wr +
              fragoff(Rw, kkw, lpb + grp * 4 + r) + cc);
          __hip_atomic_store(p, myb | (nb << 16), __ATOMIC_RELAXED,
                             __HIP_MEMORY_SCOPE_AGENT);
        }
      }
      asm volatile("s_waitcnt vmcnt(0)" ::: "memory");  // h0 stores acked
    }
    // arriveA(s+1): my h0[s] is globally visible
    if (lane == 0)
      __hip_atomic_store(&slotsA[ut * 4 + wid], (unsigned)(s + 1),
                         __ATOMIC_RELAXED, __HIP_MEMORY_SCOPE_AGENT);

    // ======== shadow: layer1 t = s-2 (inputs already visible) ========
    if (s >= 2) {
      f32x4 a10 = {bias1[0], bias1[0], bias1[0], bias1[0]};
      f32x4 a11 = {bias1[1], bias1[1], bias1[1], bias1[1]};
      // h0[s-2] (ring slot (s-2)&3): W_ih1 part
      {
        const u16* p = h0ring + (size_t)((s - 2) & 3) * SLOT +
                       fragoff(Rw, 0, lane);
#pragma unroll
        for (int kk = 0; kk < 16; ++kk) hf[kk] = ld_h8(p + (size_t)kk * 512);
#pragma unroll
        for (int kk = 0; kk < 16; ++kk) {
          bf16x8 bA = ld_lds8(&w1s[cc * 1048 + kk * 32 + lb]);
          bf16x8 bB = ld_lds8(&w1s[(16 + cc) * 1048 + kk * 32 + lb]);
          a10 = mfma16(hf[kk], bA, a10);
          a11 = mfma16(hf[kk], bB, a11);
        }
      }
      // h1[s-3] (slot (s-3)&1): W_hh1 part, guarded by pollB(>= s)
      if (s >= 3) {
        const unsigned tgtB = (unsigned)s;
        const unsigned long long* sl =
            (const unsigned long long*)slotsB + (size_t)lane * 2;
        for (;;) {
          unsigned long long q0 = __hip_atomic_load(sl, __ATOMIC_RELAXED,
                                                    __HIP_MEMORY_SCOPE_AGENT);
          unsigned long long q1 = __hip_atomic_load(sl + 1, __ATOMIC_RELAXED,
                                                    __HIP_MEMORY_SCOPE_AGENT);
          bool ok = ((unsigned)q0 >= tgtB) && ((unsigned)(q0 >> 32) >= tgtB) &&
                    ((unsigned)q1 >= tgtB) && ((unsigned)(q1 >> 32) >= tgtB);
          if (__all(ok)) break;
          __builtin_amdgcn_s_sleep(1);
        }
        const u16* p = h1ring + (size_t)((s - 3) & 1) * SLOT +
                       fragoff(Rw, 0, lane);
#pragma unroll
        for (int kk = 0; kk < 16; ++kk) hf[kk] = ld_h8(p + (size_t)kk * 512);
#pragma unroll
        for (int kk = 0; kk < 16; ++kk) {
          bf16x8 bA = ld_lds8(&w1s[cc * 1048 + (16 + kk) * 32 + lb]);
          bf16x8 bB = ld_lds8(&w1s[(16 + cc) * 1048 + (16 + kk) * 32 + lb]);
          a10 = mfma16(hf[kk], bA, a10);
          a11 = mfma16(hf[kk], bB, a11);
        }
      }
      // ---- layer1 cell -> store h1[s-2] (slot (s-2)&1) ----
      u16* h1wr = h1ring + (size_t)((s - 2) & 1) * SLOT;
#pragma unroll
      for (int r = 0; r < 4; ++r) {
        float f_p = __shfl_xor(a10[r], 8);
        float o_p = __shfl_xor(a11[r], 8);
        float ig = sigmf(a10[r]);
        float fg = sigmf(f_p);
        float gg = tanh_s(a11[r]);
        float og = sigmf(o_p);
        float cn = fg * c1[r] + ig * gg;
        c1[r] = cn;
        float hv = og * tanh_s(cn);
        unsigned myb = f2bf(hv);
        unsigned nb = (unsigned)__shfl_down((int)myb, 1);
        if (cc < 8 && (cc & 1) == 0) {
          unsigned* p = (unsigned*)(h1wr +
              fragoff(Rw, kkw, lpb + grp * 4 + r) + cc);
          __hip_atomic_store(p, myb | (nb << 16), __ATOMIC_RELAXED,
                             __HIP_MEMORY_SCOPE_AGENT);
        }
        if (cc < 8 && s == 513)
          h1fin[(size_t)(row0 + grp * 4 + r) * HH + u0 + cc] = hv;
      }
      asm volatile("s_waitcnt vmcnt(0)" ::: "memory");  // h1 stores acked
      // arriveB(s+1): my h1[s-2] is globally visible
      if (lane == 0)
        __hip_atomic_store(&slotsB[ut * 4 + wid], (unsigned)(s + 1),
                           __ATOMIC_RELAXED, __HIP_MEMORY_SCOPE_AGENT);
    }

    // ======== pollA: everyone's h0[s] visible before step s+1 ========
    if (s < 513) {
      __syncthreads();
      if (wid == 0) {
        const unsigned tgt = (unsigned)(s + 1);
        const unsigned long long* sl =
            (const unsigned long long*)slotsA + (size_t)lane * 2;
        for (;;) {
          unsigned long long q0 = __hip_atomic_load(sl, __ATOMIC_RELAXED,
                                                    __HIP_MEMORY_SCOPE_AGENT);
          unsigned long long q1 = __hip_atomic_load(sl + 1, __ATOMIC_RELAXED,
                                                    __HIP_MEMORY_SCOPE_AGENT);
          bool ok = ((unsigned)q0 >= tgt) && ((unsigned)(q0 >> 32) >= tgt) &&
                    ((unsigned)q1 >= tgt) && ((unsigned)(q1 >> 32) >= tgt);
          if (__all(ok)) break;
          __builtin_amdgcn_s_sleep(2);
        }
      }
      __syncthreads();
    }
  }
}

__global__ void fc_kernel(const float* __restrict__ h1fin,
                          const float* __restrict__ Wfc,
                          const float* __restrict__ bfc,
                          float* __restrict__ out) {
  const int wid = threadIdx.x >> 6, lane = threadIdx.x & 63;
  const int b = blockIdx.x * 4 + wid;
  float sum = 0.f;
#pragma unroll
  for (int j = 0; j < 8; ++j)
    sum += h1fin[(size_t)b * 512 + lane + 64 * j] * Wfc[lane + 64 * j];
#pragma unroll
  for (int m = 32; m; m >>= 1) sum += __shfl_xor(sum, m);
  if (lane == 0) out[b] = sum + bfc[0];
}

extern "C" void kernel_launch(void* const* d_in, const int* in_sizes, int n_in,
                              void* d_out, int out_size, void* d_ws, size_t ws_size,
                              hipStream_t stream) {
  const float* x    = (const float*)d_in[0];
  const float* Wih0 = (const float*)d_in[1];
  const float* Whh0 = (const float*)d_in[2];
  const float* bih0 = (const float*)d_in[3];
  const float* bhh0 = (const float*)d_in[4];
  const float* Wih1 = (const float*)d_in[5];
  const float* Whh1 = (const float*)d_in[6];
  const float* bih1 = (const float*)d_in[7];
  const float* bhh1 = (const float*)d_in[8];
  const float* Wfc  = (const float*)d_in[9];
  const float* bfc  = (const float*)d_in[10];

  char* ws = (char*)d_ws;
  u16* h0ring = (u16*)(ws);
  u16* h1ring = (u16*)(ws + OFF_H1RING);
  float* h1fin = (float*)(ws + OFF_H1FIN);
  unsigned* barA = (unsigned*)(ws + OFF_BAR);
  unsigned* barB = barA + 1024;
  u16* xfrag = (ws_size >= WS_NEED) ? (u16*)(ws + OFF_XFRAG) : nullptr;

  init_bar_k<<<1, 256, 0, stream>>>(barA);
  if (xfrag) xpose_k<<<4096, 256, 0, stream>>>(x, xfrag);
  lstm_persist<<<256, 256, 0, stream>>>(x, xfrag, Wih0, Whh0, bih0, bhh0,
                                        Wih1, Whh1, bih1, bhh1,
                                        h0ring, h1ring, h1fin, barA, barB);
  fc_kernel<<<64, 256, 0, stream>>>(h1fin, Wfc, bfc, (float*)d_out);
}